// Round 1
// baseline (338.992 us; speedup 1.0000x reference)
//
#include <hip/hip_runtime.h>
#include <hip/hip_bf16.h>
#include <math.h>

#define D 1024
#define BATCH 256
#define N_STEPS 48

typedef __attribute__((ext_vector_type(8))) short short8;
typedef __attribute__((ext_vector_type(4))) float f32x4;

__device__ __forceinline__ unsigned short f32_to_bf16_rne(float f) {
    union { float f; unsigned int u; } v; v.f = f;
    unsigned int u = v.u;
    u += 0x7FFFu + ((u >> 16) & 1u);
    return (unsigned short)(u >> 16);
}

// Transpose W (f32 row-major [k][j]) -> Wt (bf16 row-major [j][k])
__global__ __launch_bounds__(256) void prep_wt(const float* __restrict__ W,
                                               short* __restrict__ Wt) {
    __shared__ float tile[32][33];
    const int j0 = blockIdx.x * 32;
    const int k0 = blockIdx.y * 32;
    const int tx = threadIdx.x;   // 0..31
    const int ty = threadIdx.y;   // 0..7
    #pragma unroll
    for (int i = 0; i < 32; i += 8)
        tile[ty + i][tx] = W[(k0 + ty + i) * D + (j0 + tx)];
    __syncthreads();
    #pragma unroll
    for (int i = 0; i < 32; i += 8)
        Wt[(j0 + ty + i) * D + (k0 + tx)] = (short)f32_to_bf16_rne(tile[tx][ty + i]);
}

// c = inj + b (f32), z0 = bf16(x)
__global__ __launch_bounds__(256) void prep_zc(const float* __restrict__ x,
                                               const float* __restrict__ inj,
                                               const float* __restrict__ b,
                                               short* __restrict__ z0,
                                               float* __restrict__ c) {
    const int idx = blockIdx.x * 256 + threadIdx.x;   // 0..262143
    const float bb = b[idx & (D - 1)];
    c[idx] = inj[idx] + bb;
    z0[idx] = (short)f32_to_bf16_rne(x[idx]);
}

// One Picard step: z_out = tanh(z_in @ W + c), W given as Wt (bf16 [col][k]).
// Grid (32, 8): 32x32 output tile per WG. 4 waves split K=1024 into 256 each.
__global__ __launch_bounds__(256) void iter_kernel(
    const short* __restrict__ z_in, const short* __restrict__ Wt,
    const float* __restrict__ cmat, short* __restrict__ z_out,
    float* __restrict__ out_f32, int write_f32)
{
    __shared__ float red[4 * 1024];
    const int tid  = threadIdx.x;
    const int lane = tid & 63;
    const int w    = tid >> 6;          // wave id 0..3 (K-split)
    const int lrow = lane & 15;
    const int lk   = (lane >> 4) * 8;
    const int r0 = blockIdx.y * 32;
    const int c0 = blockIdx.x * 32;

    // A frag: z[r0+lrow + 16*ai][kb + lk .. +8)   (row-major, contiguous k)
    // B frag: Wt[c0+lrow + 16*bi][kb + lk .. +8)  == W[k][col], contiguous k
    const short* a0p = z_in + (r0 + lrow) * D + (w * 256 + lk);
    const short* b0p = Wt   + (c0 + lrow) * D + (w * 256 + lk);

    f32x4 acc00 = {0.f,0.f,0.f,0.f}, acc01 = {0.f,0.f,0.f,0.f};
    f32x4 acc10 = {0.f,0.f,0.f,0.f}, acc11 = {0.f,0.f,0.f,0.f};

    short8 a0 = *(const short8*)(a0p);
    short8 a1 = *(const short8*)(a0p + 16 * D);
    short8 b0 = *(const short8*)(b0p);
    short8 b1 = *(const short8*)(b0p + 16 * D);

    #pragma unroll
    for (int kb = 32; kb <= 256; kb += 32) {
        short8 na0, na1, nb0, nb1;
        if (kb < 256) {
            na0 = *(const short8*)(a0p + kb);
            na1 = *(const short8*)(a0p + 16 * D + kb);
            nb0 = *(const short8*)(b0p + kb);
            nb1 = *(const short8*)(b0p + 16 * D + kb);
        }
        acc00 = __builtin_amdgcn_mfma_f32_16x16x32_bf16(a0, b0, acc00, 0, 0, 0);
        acc01 = __builtin_amdgcn_mfma_f32_16x16x32_bf16(a0, b1, acc01, 0, 0, 0);
        acc10 = __builtin_amdgcn_mfma_f32_16x16x32_bf16(a1, b0, acc10, 0, 0, 0);
        acc11 = __builtin_amdgcn_mfma_f32_16x16x32_bf16(a1, b1, acc11, 0, 0, 0);
        a0 = na0; a1 = na1; b0 = nb0; b1 = nb1;
    }

    // Stash per-wave partials in natural (r_local, c_local) order.
    {
        const int rl = (lane >> 4) * 4;
        const int cl = lane & 15;
        float* base = &red[w * 1024];
        #pragma unroll
        for (int q = 0; q < 4; ++q) {
            base[(rl + q) * 32 + cl]           = acc00[q];
            base[(rl + q) * 32 + cl + 16]      = acc01[q];
            base[(rl + 16 + q) * 32 + cl]      = acc10[q];
            base[(rl + 16 + q) * 32 + cl + 16] = acc11[q];
        }
    }
    __syncthreads();

    // Reduce 4 K-partials, add c, tanh, write (coalesced 32-element runs).
    #pragma unroll
    for (int s = 0; s < 4; ++s) {
        const int e = tid + s * 256;              // 0..1023
        float v = red[e] + red[1024 + e] + red[2048 + e] + red[3072 + e];
        const int r  = r0 + (e >> 5);
        const int cc = c0 + (e & 31);
        v = tanhf(v + cmat[r * D + cc]);
        if (write_f32) out_f32[r * D + cc] = v;
        else           z_out[r * D + cc] = (short)f32_to_bf16_rne(v);
    }
}

extern "C" void kernel_launch(void* const* d_in, const int* in_sizes, int n_in,
                              void* d_out, int out_size, void* d_ws, size_t ws_size,
                              hipStream_t stream) {
    const float* x   = (const float*)d_in[0];
    const float* W   = (const float*)d_in[1];
    const float* b   = (const float*)d_in[2];
    const float* inj = (const float*)d_in[3];
    float* out = (float*)d_out;

    char* ws = (char*)d_ws;
    short* Wt = (short*)ws;                               // 2 MB bf16 W^T
    float* c  = (float*)(ws + 2 * 1024 * 1024);           // 1 MB f32 (inj+b)
    short* zA = (short*)(ws + 3 * 1024 * 1024);           // 512 KB bf16
    short* zB = (short*)(ws + 3 * 1024 * 1024 + 512 * 1024);

    prep_wt<<<dim3(32, 32), dim3(32, 8), 0, stream>>>(W, Wt);
    prep_zc<<<dim3(1024), dim3(256), 0, stream>>>(x, inj, b, zA, c);

    short* zin = zA;
    short* zout = zB;
    for (int t = 0; t < N_STEPS; ++t) {
        const int last = (t == N_STEPS - 1) ? 1 : 0;
        iter_kernel<<<dim3(32, 8), dim3(256), 0, stream>>>(zin, Wt, c, zout, out, last);
        short* tmp = zin; zin = zout; zout = tmp;
    }
}